// Round 9
// baseline (469.557 us; speedup 1.0000x reference)
//
#include <hip/hip_runtime.h>

// g2[b,c,h,w] = sum_d cost[b,d,h,w] * h1[b,c,h,w+d]   (w+d < W, else 0)
// B=4 C=32 H=256 W=512 D=48, fp32.
//
// v7b: v7 with the nontemporal-store type fixed (clang builtin needs a
// native vector type, not HIP's float4 class). Structure unchanged:
//   - no-LDS register sliding window (v6 mechanism, LDS pipe eliminated).
//   - 4 channels/wave (was 2 in v6): 8 FMA/load; cost redundancy per
//     tile 4x -> 2x (FETCH was the v6 regression: 128->198 MB).
//   - cv double-buffer, distance-1 prefetch, fully unrolled (static
//     indices only). Live regs ~100 < 128 cap from launch_bounds(256,4).
//   - template<MASK>: wstart=0 half needs NO tail masking (max operand
//     index 303 < 512) -> no clamp/cndmask on half the grid.
//   - paired blocks (same tile, cgrp 0/1) placed 8 apart in blockIdx ->
//     same XCD -> cost's 2nd read hits that XCD's L2.
//   - nontemporal out stores (write-once data; keep L2/L3 for inputs).
//   - explicit fmaf to pin fused accumulation order.

#define BB 4
#define CC 32
#define HH 256
#define WW 512
#define DDISP 48
#define HW (HH * WW)     // 131072
#define TW 256
#define NT 256

typedef float f32x4 __attribute__((ext_vector_type(4)));

// h1 quad load. Quads are 4-aligned and W%4==0 -> fully in or fully out.
template<bool MASK>
__device__ __forceinline__ void ldq(const float* __restrict__ row, int wq,
                                    float* __restrict__ dst)
{
    if (MASK) {
        int wc = wq > (WW - 4) ? (WW - 4) : wq;   // clamp keeps addr in-row
        float4 t = *(const float4*)(row + wc);
        bool ok = wq < WW;
        dst[0] = ok ? t.x : 0.f;
        dst[1] = ok ? t.y : 0.f;
        dst[2] = ok ? t.z : 0.f;
        dst[3] = ok ? t.w : 0.f;
    } else {
        float4 t = *(const float4*)(row + wq);
        dst[0] = t.x; dst[1] = t.y; dst[2] = t.z; dst[3] = t.w;
    }
}

template<bool MASK>
__device__ __forceinline__ void body(const float* __restrict__ h1,
                                     const float* __restrict__ cost,
                                     float* __restrict__ out,
                                     int b, int h, int cgrp, int wstart)
{
    const int lane = threadIdx.x & 63;
    const int wid  = threadIdx.x >> 6;           // 0..3
    const int c0   = (cgrp << 4) + (wid << 2);   // 4 channels/wave, 16/block
    const int w0   = lane << 2;
    const int wq0  = wstart + w0;                // lane's first output w

    const float* r[4];
#pragma unroll
    for (int c = 0; c < 4; ++c)
        r[c] = h1 + (((size_t)(b * CC + c0 + c)) * HH + h) * WW;

    float acc[4][4];
#pragma unroll
    for (int c = 0; c < 4; ++c)
#pragma unroll
        for (int j = 0; j < 4; ++j) acc[c][j] = 0.f;

    // win[c][slot*4+k]: circular 2-quad window. Invariant at start of
    // group g: slot (g&1) = h1 quad at wq0+4g, slot ((g+1)&1) = wq0+4g+4.
    float win[4][8];
#pragma unroll
    for (int c = 0; c < 4; ++c) {
        ldq<false>(r[c], wq0, &win[c][0]);       // wq0 <= 508: never OOB
        ldq<MASK >(r[c], wq0 + 4, &win[c][4]);   // wq0+4 can hit 512
    }

    const float* cp = cost + ((size_t)(b * DDISP) * HH + h) * WW + wq0;

    // cost double-buffer: group g consumes cv[g&1]; loads for g+1 are
    // issued before g's FMAs. Fully unrolled -> all indices static.
    float cv[2][4][4];
#pragma unroll
    for (int dd = 0; dd < 4; ++dd) {
        float4 t = *(const float4*)(cp + (size_t)dd * HW);
        cv[0][dd][0] = t.x; cv[0][dd][1] = t.y;
        cv[0][dd][2] = t.z; cv[0][dd][3] = t.w;
    }

#pragma unroll
    for (int g = 0; g < 12; ++g) {
        const int cur = g & 1;
        const int nxt = cur ^ 1;
        if (g < 11) {
            // prefetch next group's cost rows (independent of this group)
#pragma unroll
            for (int dd = 0; dd < 4; ++dd) {
                float4 t = *(const float4*)(cp + (size_t)(4 * (g + 1) + dd) * HW);
                cv[nxt][dd][0] = t.x; cv[nxt][dd][1] = t.y;
                cv[nxt][dd][2] = t.z; cv[nxt][dd][3] = t.w;
            }
        }
        // FMAs: group g covers d = 4g..4g+3; output j needs operand
        // wq0+4g+(dd+j), dd+j in 0..6 -> window quads [4g, 4g+7].
#pragma unroll
        for (int c = 0; c < 4; ++c)
#pragma unroll
            for (int dd = 0; dd < 4; ++dd)
#pragma unroll
                for (int j = 0; j < 4; ++j) {
                    const int o    = dd + j;               // 0..6
                    const int slot = (cur + (o >> 2)) & 1;
                    acc[c][j] = __builtin_fmaf(cv[cur][dd][j],
                                               win[c][slot * 4 + (o & 3)],
                                               acc[c][j]);
                }
        if (g < 11) {
            // slide: overwrite dead slot (cur) with quad 4g+8 (for g+1)
#pragma unroll
            for (int c = 0; c < 4; ++c)
                ldq<MASK>(r[c], wq0 + 4 * g + 8, &win[c][cur * 4]);
        }
    }

    float* ob = out + (((size_t)(b * CC + c0)) * HH + h) * WW + wq0;
#pragma unroll
    for (int c = 0; c < 4; ++c) {
        f32x4 v = { acc[c][0], acc[c][1], acc[c][2], acc[c][3] };
        __builtin_nontemporal_store(v, (f32x4*)(ob + (size_t)c * HW));
    }
}

__global__ __launch_bounds__(NT, 4)
void dense_warp_kernel(const float* __restrict__ h1,
                       const float* __restrict__ cost,
                       float* __restrict__ out)
{
    const int blk  = blockIdx.x;          // 0..4095
    const int blk2 = blk & 2047;
    // pair (cgrp 0/1 of one tile) 8 apart -> same XCD under round-robin
    const int sub  = blk2 & 7;
    const int cgrp = (blk2 >> 3) & 1;
    const int tile = ((blk2 >> 4) << 3) | sub;   // 0..1023 = (b,h)
    const int b    = tile >> 8;
    const int h    = tile & 255;

    if (blk < 2048) body<false>(h1, cost, out, b, h, cgrp, 0);
    else            body<true >(h1, cost, out, b, h, cgrp, TW);
}

extern "C" void kernel_launch(void* const* d_in, const int* in_sizes, int n_in,
                              void* d_out, int out_size, void* d_ws, size_t ws_size,
                              hipStream_t stream) {
    const float* h1   = (const float*)d_in[0];
    const float* cost = (const float*)d_in[1];
    float* out        = (float*)d_out;
    dim3 grid(BB * HH * 2 * 2);   // 4096: [wside | tile-hi | cgrp | tile-lo(3)]
    dense_warp_kernel<<<grid, NT, 0, stream>>>(h1, cost, out);
}